// Round 4
// baseline (575.468 us; speedup 1.0000x reference)
//
#include <hip/hip_runtime.h>
#include <math.h>

using bf16x8 = __attribute__((ext_vector_type(8))) short;
using f32x4  = __attribute__((ext_vector_type(4))) float;
using u16x8  = __attribute__((ext_vector_type(8))) unsigned short;
using u16x4  = __attribute__((ext_vector_type(4))) unsigned short;

constexpr int Bb = 4, Tt = 2048, Ee = 1024, Hh = 16;
constexpr int Mm = Bb * Tt;   // 8192
constexpr int E3 = 3 * Ee;    // 3072

__device__ __forceinline__ unsigned short f2bf(float f) {
  union { float f; unsigned int u; } c; c.f = f;
  unsigned int u = c.u;
  u += 0x7fffu + ((u >> 16) & 1u);   // RNE
  return (unsigned short)(u >> 16);
}

__device__ __forceinline__ f32x4 mfma16(bf16x8 a, bf16x8 b, f32x4 c) {
  return __builtin_amdgcn_mfma_f32_16x16x32_bf16(a, b, c, 0, 0, 0);
}

__device__ __forceinline__ void gload_lds16(const unsigned short* g, unsigned short* l) {
  __builtin_amdgcn_global_load_lds(
      (const __attribute__((address_space(1))) unsigned int*)g,
      (__attribute__((address_space(3))) unsigned int*)l, 16, 0, 0);
}

// ---------------------------------------------------------------------------
// fused fp32 -> bf16 conversion for all three inputs (one launch)
// ---------------------------------------------------------------------------
__global__ void cvt_all(const float* __restrict__ q, const float* __restrict__ iw,
                        const float* __restrict__ ow, unsigned short* __restrict__ qb,
                        unsigned short* __restrict__ wib, unsigned short* __restrict__ wob) {
  constexpr int nQ = Mm * Ee / 8, nI = E3 * Ee / 8, nO = Ee * Ee / 8;
  int i = blockIdx.x * 256 + threadIdx.x;
  const float* in; unsigned short* out;
  if (i < nQ) { in = q; out = qb; }
  else if (i < nQ + nI) { in = iw; out = wib; i -= nQ; }
  else if (i < nQ + nI + nO) { in = ow; out = wob; i -= nQ + nI; }
  else return;
  const float4* p = (const float4*)in + (size_t)i * 2;
  const float4 a = p[0], b = p[1];
  u16x8 r = { f2bf(a.x), f2bf(a.y), f2bf(a.z), f2bf(a.w),
              f2bf(b.x), f2bf(b.y), f2bf(b.z), f2bf(b.w) };
  *(u16x8*)(out + (size_t)i * 8) = r;
}

// ---------------------------------------------------------------------------
// C[M,N] = A[M,K] * Bw[N,K]^T + bias  (bf16 MFMA, m97-style)
// QSCALE: cols<1024 (q part) scaled by log2(e)/8 after bias (exp2 trick).
// ---------------------------------------------------------------------------
template <bool OUT_BF16, bool QSCALE>
__global__ __launch_bounds__(256, 2)
void gemm_bt(const unsigned short* __restrict__ A, const unsigned short* __restrict__ Bw,
             const float* __restrict__ bias, void* __restrict__ Cout, int N, int K) {
  __shared__ alignas(16) unsigned short As[128 * 32];
  __shared__ alignas(16) unsigned short Bs[128 * 32];
  const int tid = threadIdx.x;
  const int wave = tid >> 6, lane = tid & 63;
  const int l15 = lane & 15, quad = lane >> 4;
  const int wr = wave >> 1, wc = wave & 1;
  const int row0 = blockIdx.y * 128, col0 = blockIdx.x * 128;
  const int srow = lane >> 2, sslot = lane & 3;

  f32x4 acc[4][4];
#pragma unroll
  for (int i = 0; i < 4; ++i)
#pragma unroll
    for (int j = 0; j < 4; ++j) acc[i][j] = f32x4{0.f, 0.f, 0.f, 0.f};

  for (int k0 = 0; k0 < K; k0 += 32) {
#pragma unroll
    for (int t = 0; t < 2; ++t) {
      const int rA = wave * 32 + t * 16 + srow;          // 0..127
      const int g = sslot ^ ((rA >> 1) & 3);             // swizzled global chunk
      gload_lds16(A  + (size_t)(row0 + rA) * K + k0 + g * 8, &As[(wave * 32 + t * 16) * 32]);
      gload_lds16(Bw + (size_t)(col0 + rA) * K + k0 + g * 8, &Bs[(wave * 32 + t * 16) * 32]);
    }
    __syncthreads();

    bf16x8 af[4], bfr[4];
#pragma unroll
    for (int mi = 0; mi < 4; ++mi) {
      const int m = wr * 64 + mi * 16 + l15;
      af[mi] = *(const bf16x8*)&As[m * 32 + (quad ^ ((m >> 1) & 3)) * 8];
    }
#pragma unroll
    for (int ni = 0; ni < 4; ++ni) {
      const int n = wc * 64 + ni * 16 + l15;
      bfr[ni] = *(const bf16x8*)&Bs[n * 32 + (quad ^ ((n >> 1) & 3)) * 8];
    }
#pragma unroll
    for (int mi = 0; mi < 4; ++mi)
#pragma unroll
      for (int ni = 0; ni < 4; ++ni) acc[mi][ni] = mfma16(af[mi], bfr[ni], acc[mi][ni]);
    __syncthreads();
  }

#pragma unroll
  for (int mi = 0; mi < 4; ++mi)
#pragma unroll
    for (int ni = 0; ni < 4; ++ni) {
      const int col = col0 + wc * 64 + ni * 16 + l15;
      const float bv = bias[col];
      const float scale = (QSCALE && col < 1024) ? 0.18033688f : 1.0f;  // log2(e)/8
#pragma unroll
      for (int r = 0; r < 4; ++r) {
        const int row = row0 + wr * 64 + mi * 16 + quad * 4 + r;
        float v = (acc[mi][ni][r] + bv) * scale;
        if (OUT_BF16)
          ((unsigned short*)Cout)[(size_t)row * N + col] = f2bf(v);
        else
          ((float*)Cout)[(size_t)row * N + col] = v;
      }
    }
}

// ---------------------------------------------------------------------------
// V transpose: vt[b][h][d][t] <- qkv v-part [b][t][2048 + h*64 + d]
// ---------------------------------------------------------------------------
__global__ __launch_bounds__(256, 2)
void transpose_v(const unsigned short* __restrict__ qkv, unsigned short* __restrict__ vt) {
  __shared__ unsigned short L[128][66];
  const int tid = threadIdx.x;
  const int bh = blockIdx.x, b = bh >> 4, h = bh & 15;
  const int t0 = blockIdx.y * 128;
#pragma unroll
  for (int p = 0; p < 8; ++p) {
    const int tl = p * 16 + (tid >> 4);
    const int d = (tid & 15) * 4;
    *(u16x4*)&L[tl][d] = *(const u16x4*)(qkv + (size_t)(b * Tt + t0 + tl) * E3 + 2 * Ee + h * 64 + d);
  }
  __syncthreads();
#pragma unroll
  for (int p = 0; p < 8; ++p) {
    const int dw = (tid >> 5) * 8 + p;
    const int tw = (tid & 31) * 4;
    u16x4 w = { L[tw][dw], L[tw + 1][dw], L[tw + 2][dw], L[tw + 3][dw] };
    *(u16x4*)(vt + ((size_t)bh * 64 + dw) * Tt + t0 + tw) = w;
  }
}

// ---------------------------------------------------------------------------
// Fused attention with KEY-SPLIT. Wave = 64 q-rows x 1024 keys (half stream).
// Block = 4 waves = 2 q-tiles x 2 k-halves -> 4096 waves total (4/SIMD).
// S^T = MFMA(A=K, B=Q); exp2; perm-pack; per-wave-private LDS P (swizzled);
// PV with A=P, B=V^T direct from global; l = P.1 via ones-MFMA.
// No running max -> k-split partials (O,l) combine by addition through LDS.
// ---------------------------------------------------------------------------
__global__ __launch_bounds__(256, 4)
void attn_mfma3(const unsigned short* __restrict__ qkv,
                const unsigned short* __restrict__ vt,
                unsigned short* __restrict__ ctx) {
  // union: during k-loop 4x4096 shorts (per-wave P); after, 2x5120 f32x4 slots
  __shared__ alignas(16) char lds[40960];
  const int tid = threadIdx.x;
  const int wave = tid >> 6, lane = tid & 63;
  const int l15 = lane & 15, quad = lane >> 4;
  const int pair = wave >> 1, kh = wave & 1;
  const int bh = blockIdx.x, b = bh >> 4, h = bh & 15;
  const int q0 = blockIdx.y * 128 + pair * 64;
  unsigned short* const ps = (unsigned short*)lds + wave * 4096;
  const int swz = l15 & 14;

  // Q fragments (B operand): q = q0 + qi*16 + l15, d = kf*32 + quad*8
  bf16x8 qa[4][2];
#pragma unroll
  for (int qi = 0; qi < 4; ++qi)
#pragma unroll
    for (int kf = 0; kf < 2; ++kf)
      qa[qi][kf] = *(const bf16x8*)(qkv +
          (size_t)(b * Tt + q0 + qi * 16 + l15) * E3 + h * 64 + kf * 32 + quad * 8);

  f32x4 o[4][4], ol[4];
#pragma unroll
  for (int qi = 0; qi < 4; ++qi) {
    ol[qi] = f32x4{0.f, 0.f, 0.f, 0.f};
#pragma unroll
    for (int di = 0; di < 4; ++di) o[qi][di] = f32x4{0.f, 0.f, 0.f, 0.f};
  }
  bf16x8 ones;
#pragma unroll
  for (int i = 0; i < 8; ++i) ones[i] = (short)0x3F80;  // bf16 1.0

  const unsigned short* kp =
      qkv + (size_t)(b * Tt + kh * 1024 + l15) * E3 + Ee + h * 64 + quad * 8;
  const unsigned short* vp = vt + ((size_t)bh * 64 + l15) * Tt + kh * 1024 + quad * 8;

  for (int it = 0; it < 16; ++it) {   // 16 x 64 keys = this wave's half
    bf16x8 vb[4][2], kb[4][2];
#pragma unroll
    for (int di = 0; di < 4; ++di)
#pragma unroll
      for (int kf = 0; kf < 2; ++kf)
        vb[di][kf] = *(const bf16x8*)(vp + di * 16 * Tt + kf * 32);
#pragma unroll
    for (int ki = 0; ki < 4; ++ki)
#pragma unroll
      for (int kf = 0; kf < 2; ++kf)
        kb[ki][kf] = *(const bf16x8*)(kp + (size_t)ki * 16 * E3 + kf * 32);

    // S^T tiles: row = key (quad*4+r), col = q (l15); exp2 + pack + LDS write
#pragma unroll
    for (int ki = 0; ki < 4; ++ki) {
      f32x4 s[4];
#pragma unroll
      for (int qi = 0; qi < 4; ++qi) {
        s[qi] = mfma16(kb[ki][0], qa[qi][0], f32x4{0.f, 0.f, 0.f, 0.f});
        s[qi] = mfma16(kb[ki][1], qa[qi][1], s[qi]);
      }
#pragma unroll
      for (int qi = 0; qi < 4; ++qi) {
        const float e0 = __builtin_amdgcn_exp2f(s[qi][0]);
        const float e1 = __builtin_amdgcn_exp2f(s[qi][1]);
        const float e2 = __builtin_amdgcn_exp2f(s[qi][2]);
        const float e3 = __builtin_amdgcn_exp2f(s[qi][3]);
        uint2 w;  // truncate-to-bf16 pairs (bias cancels: denom uses same P)
        w.x = __builtin_amdgcn_perm(__float_as_uint(e1), __float_as_uint(e0), 0x07060302u);
        w.y = __builtin_amdgcn_perm(__float_as_uint(e3), __float_as_uint(e2), 0x07060302u);
        *(uint2*)(ps + (qi * 16 + l15) * 64 + (((ki * 4 + quad) ^ swz) << 2)) = w;
      }
    }
    __asm__ volatile("s_waitcnt lgkmcnt(0)" ::: "memory");

    // P A-frags (vector reads), then l += P.1 and O += P.V
    bf16x8 pa[4][2];
#pragma unroll
    for (int qi = 0; qi < 4; ++qi)
#pragma unroll
      for (int kf = 0; kf < 2; ++kf)
        pa[qi][kf] = *(const bf16x8*)(ps + (qi * 16 + l15) * 64 + (((kf * 8 + quad * 2) ^ swz) << 2));
#pragma unroll
    for (int qi = 0; qi < 4; ++qi) {
      ol[qi] = mfma16(pa[qi][0], ones, ol[qi]);
      ol[qi] = mfma16(pa[qi][1], ones, ol[qi]);
#pragma unroll
      for (int di = 0; di < 4; ++di) {
        o[qi][di] = mfma16(pa[qi][0], vb[di][0], o[qi][di]);
        o[qi][di] = mfma16(pa[qi][1], vb[di][1], o[qi][di]);
      }
    }
    kp += 64 * E3;
    vp += 64;
  }

  // ---- combine k-halves: odd waves dump (O,l) to LDS; even waves add+store
  __syncthreads();   // all waves done with their P slabs
  f32x4* const ex = (f32x4*)lds + (size_t)pair * 1280;  // 20 slots x 64 lanes
  if (kh == 1) {
#pragma unroll
    for (int qi = 0; qi < 4; ++qi) {
#pragma unroll
      for (int di = 0; di < 4; ++di) ex[(qi * 4 + di) * 64 + lane] = o[qi][di];
      ex[(16 + qi) * 64 + lane] = ol[qi];
    }
  }
  __syncthreads();
  if (kh == 0) {
#pragma unroll
    for (int qi = 0; qi < 4; ++qi) {
      const f32x4 l2 = ex[(16 + qi) * 64 + lane];
      f32x4 inv;
#pragma unroll
      for (int r = 0; r < 4; ++r) inv[r] = 1.0f / (ol[qi][r] + l2[r]);
#pragma unroll
      for (int di = 0; di < 4; ++di) {
        const f32x4 o2 = ex[(qi * 4 + di) * 64 + lane];
#pragma unroll
        for (int r = 0; r < 4; ++r)
          ctx[(size_t)(b * Tt + q0 + qi * 16 + quad * 4 + r) * Ee + h * 64 + di * 16 + l15] =
              f2bf((o[qi][di][r] + o2[r]) * inv[r]);
      }
    }
  }
}

// ---------------------------------------------------------------------------
extern "C" void kernel_launch(void* const* d_in, const int* in_sizes, int n_in,
                              void* d_out, int out_size, void* d_ws, size_t ws_size,
                              hipStream_t stream) {
  const float* query = (const float*)d_in[0];
  const float* in_w  = (const float*)d_in[1];
  const float* in_b  = (const float*)d_in[2];
  const float* out_w = (const float*)d_in[3];
  const float* out_b = (const float*)d_in[4];
  float* out = (float*)d_out;

  char* w = (char*)d_ws;
  unsigned short* qkvb = (unsigned short*)(w);                 // 48 MiB
  unsigned short* ctxb = (unsigned short*)(w + 50331648);      // 16 MiB
  unsigned short* qb   = (unsigned short*)(w + 67108864);      // 16 MiB
  unsigned short* wib  = (unsigned short*)(w + 83886080);      // 6 MiB
  unsigned short* wob  = (unsigned short*)(w + 90177536);      // 2 MiB
  unsigned short* vtb  = (unsigned short*)(w + 92274688);      // 16 MiB

  // 0) all fp32->bf16 conversions in one launch
  cvt_all<<<6144, 256, 0, stream>>>(query, in_w, out_w, qb, wib, wob);
  // 1) qkv = query @ in_w^T + in_b  (q part pre-scaled by log2e/8, bf16)
  gemm_bt<true, true><<<dim3(E3 / 128, Mm / 128), 256, 0, stream>>>(qb, wib, in_b, qkvb, E3, Ee);
  // 1b) pre-transpose V: vt[b][h][d][t]
  transpose_v<<<dim3(Bb * Hh, Tt / 128), 256, 0, stream>>>(qkvb, vtb);
  // 2) fused attention (key-split x2) -> ctx (bf16, [B,T,E])
  attn_mfma3<<<dim3(Bb * Hh, Tt / 128), 256, 0, stream>>>(qkvb, vtb, ctxb);
  // 3) out = ctx @ out_w^T + out_b  (fp32 out)
  gemm_bt<false, false><<<dim3(Ee / 128, Mm / 128), 256, 0, stream>>>(ctxb, wob, out_b, out, Ee, Ee);
}

// Round 5
// 313.068 us; speedup vs baseline: 1.8382x; 1.8382x over previous
//
#include <hip/hip_runtime.h>
#include <math.h>

using bf16x8 = __attribute__((ext_vector_type(8))) short;
using f32x4  = __attribute__((ext_vector_type(4))) float;
using u16x8  = __attribute__((ext_vector_type(8))) unsigned short;
using u16x4  = __attribute__((ext_vector_type(4))) unsigned short;

constexpr int Bb = 4, Tt = 2048, Ee = 1024, Hh = 16;
constexpr int Mm = Bb * Tt;   // 8192
constexpr int E3 = 3 * Ee;    // 3072

__device__ __forceinline__ unsigned short f2bf(float f) {
  union { float f; unsigned int u; } c; c.f = f;
  unsigned int u = c.u;
  u += 0x7fffu + ((u >> 16) & 1u);   // RNE
  return (unsigned short)(u >> 16);
}

__device__ __forceinline__ f32x4 mfma16(bf16x8 a, bf16x8 b, f32x4 c) {
  return __builtin_amdgcn_mfma_f32_16x16x32_bf16(a, b, c, 0, 0, 0);
}

__device__ __forceinline__ void gload_lds16(const unsigned short* g, unsigned short* l) {
  __builtin_amdgcn_global_load_lds(
      (const __attribute__((address_space(1))) unsigned int*)g,
      (__attribute__((address_space(3))) unsigned int*)l, 16, 0, 0);
}

// ---------------------------------------------------------------------------
// fused fp32 -> bf16 conversion for all three inputs (one launch)
// ---------------------------------------------------------------------------
__global__ void cvt_all(const float* __restrict__ q, const float* __restrict__ iw,
                        const float* __restrict__ ow, unsigned short* __restrict__ qb,
                        unsigned short* __restrict__ wib, unsigned short* __restrict__ wob) {
  constexpr int nQ = Mm * Ee / 8, nI = E3 * Ee / 8, nO = Ee * Ee / 8;
  int i = blockIdx.x * 256 + threadIdx.x;
  const float* in; unsigned short* out;
  if (i < nQ) { in = q; out = qb; }
  else if (i < nQ + nI) { in = iw; out = wib; i -= nQ; }
  else if (i < nQ + nI + nO) { in = ow; out = wob; i -= nQ + nI; }
  else return;
  const float4* p = (const float4*)in + (size_t)i * 2;
  const float4 a = p[0], b = p[1];
  u16x8 r = { f2bf(a.x), f2bf(a.y), f2bf(a.z), f2bf(a.w),
              f2bf(b.x), f2bf(b.y), f2bf(b.z), f2bf(b.w) };
  *(u16x8*)(out + (size_t)i * 8) = r;
}

// ---------------------------------------------------------------------------
// C[M,N] = A[M,K] * Bw[N,K]^T + bias  (bf16 MFMA, m97-style)
// QSCALE: cols<1024 (q part) scaled by log2(e)/8 after bias (exp2 trick).
// ---------------------------------------------------------------------------
template <bool OUT_BF16, bool QSCALE>
__global__ __launch_bounds__(256, 2)
void gemm_bt(const unsigned short* __restrict__ A, const unsigned short* __restrict__ Bw,
             const float* __restrict__ bias, void* __restrict__ Cout, int N, int K) {
  __shared__ alignas(16) unsigned short As[128 * 32];
  __shared__ alignas(16) unsigned short Bs[128 * 32];
  const int tid = threadIdx.x;
  const int wave = tid >> 6, lane = tid & 63;
  const int l15 = lane & 15, quad = lane >> 4;
  const int wr = wave >> 1, wc = wave & 1;
  const int row0 = blockIdx.y * 128, col0 = blockIdx.x * 128;
  const int srow = lane >> 2, sslot = lane & 3;

  f32x4 acc[4][4];
#pragma unroll
  for (int i = 0; i < 4; ++i)
#pragma unroll
    for (int j = 0; j < 4; ++j) acc[i][j] = f32x4{0.f, 0.f, 0.f, 0.f};

  for (int k0 = 0; k0 < K; k0 += 32) {
#pragma unroll
    for (int t = 0; t < 2; ++t) {
      const int rA = wave * 32 + t * 16 + srow;          // 0..127
      const int g = sslot ^ ((rA >> 1) & 3);             // swizzled global chunk
      gload_lds16(A  + (size_t)(row0 + rA) * K + k0 + g * 8, &As[(wave * 32 + t * 16) * 32]);
      gload_lds16(Bw + (size_t)(col0 + rA) * K + k0 + g * 8, &Bs[(wave * 32 + t * 16) * 32]);
    }
    __syncthreads();

    bf16x8 af[4], bfr[4];
#pragma unroll
    for (int mi = 0; mi < 4; ++mi) {
      const int m = wr * 64 + mi * 16 + l15;
      af[mi] = *(const bf16x8*)&As[m * 32 + (quad ^ ((m >> 1) & 3)) * 8];
    }
#pragma unroll
    for (int ni = 0; ni < 4; ++ni) {
      const int n = wc * 64 + ni * 16 + l15;
      bfr[ni] = *(const bf16x8*)&Bs[n * 32 + (quad ^ ((n >> 1) & 3)) * 8];
    }
#pragma unroll
    for (int mi = 0; mi < 4; ++mi)
#pragma unroll
      for (int ni = 0; ni < 4; ++ni) acc[mi][ni] = mfma16(af[mi], bfr[ni], acc[mi][ni]);
    __syncthreads();
  }

#pragma unroll
  for (int mi = 0; mi < 4; ++mi)
#pragma unroll
    for (int ni = 0; ni < 4; ++ni) {
      const int col = col0 + wc * 64 + ni * 16 + l15;
      const float bv = bias[col];
      const float scale = (QSCALE && col < 1024) ? 0.18033688f : 1.0f;  // log2(e)/8
#pragma unroll
      for (int r = 0; r < 4; ++r) {
        const int row = row0 + wr * 64 + mi * 16 + quad * 4 + r;
        float v = (acc[mi][ni][r] + bv) * scale;
        if (OUT_BF16)
          ((unsigned short*)Cout)[(size_t)row * N + col] = f2bf(v);
        else
          ((float*)Cout)[(size_t)row * N + col] = v;
      }
    }
}

// ---------------------------------------------------------------------------
// V transpose: vt[b][h][d][t] <- qkv v-part [b][t][2048 + h*64 + d]
// ---------------------------------------------------------------------------
__global__ __launch_bounds__(256, 2)
void transpose_v(const unsigned short* __restrict__ qkv, unsigned short* __restrict__ vt) {
  __shared__ unsigned short L[128][66];
  const int tid = threadIdx.x;
  const int bh = blockIdx.x, b = bh >> 4, h = bh & 15;
  const int t0 = blockIdx.y * 128;
#pragma unroll
  for (int p = 0; p < 8; ++p) {
    const int tl = p * 16 + (tid >> 4);
    const int d = (tid & 15) * 4;
    *(u16x4*)&L[tl][d] = *(const u16x4*)(qkv + (size_t)(b * Tt + t0 + tl) * E3 + 2 * Ee + h * 64 + d);
  }
  __syncthreads();
#pragma unroll
  for (int p = 0; p < 8; ++p) {
    const int dw = (tid >> 5) * 8 + p;
    const int tw = (tid & 31) * 4;
    u16x4 w = { L[tw][dw], L[tw + 1][dw], L[tw + 2][dw], L[tw + 3][dw] };
    *(u16x4*)(vt + ((size_t)bh * 64 + dw) * Tt + t0 + tw) = w;
  }
}

// ---------------------------------------------------------------------------
// Fused attention, barrier-free, software-pipelined. Wave = 64 q-rows;
// block = 4 waves. j-tile = 64 keys. S^T = MFMA(A=K, B=Q) -> exp2 ->
// perm-pack -> ds_write_b64 into per-wave-private swizzled Ps[q][key];
// PV: A = P (ds_read_b128), B = V^T direct from global (pre-transposed);
// denominator l = P.ones MFMA (layout-matched, same quantized P).
// Pipelining: kb[ki] reloaded for the NEXT iter right after its last S-MFMA;
// vb reloaded after its last PV use; last iteration peeled (no OOB prefetch).
// No asm waitcnt/clobber -- compiler inserts minimal lgkm waits and can keep
// next-iter global loads in flight across the LDS round-trip.
// ---------------------------------------------------------------------------
__global__ __launch_bounds__(256, 2)
void attn_mfma4(const unsigned short* __restrict__ qkv,
                const unsigned short* __restrict__ vt,
                unsigned short* __restrict__ ctx) {
  __shared__ alignas(16) unsigned short Ps[4 * 4096];  // per-wave 64x64 bf16
  const int tid = threadIdx.x;
  const int wave = tid >> 6, lane = tid & 63;
  const int l15 = lane & 15, quad = lane >> 4;
  const int bh = blockIdx.x, b = bh >> 4, h = bh & 15;
  const int q0 = blockIdx.y * 256 + wave * 64;
  unsigned short* const ps = &Ps[wave * 4096];
  const int swz = l15 & 14;

  // Q fragments (B operand): q = q0 + qi*16 + l15, d = kf*32 + quad*8
  bf16x8 qa[4][2];
#pragma unroll
  for (int qi = 0; qi < 4; ++qi)
#pragma unroll
    for (int kf = 0; kf < 2; ++kf)
      qa[qi][kf] = *(const bf16x8*)(qkv +
          (size_t)(b * Tt + q0 + qi * 16 + l15) * E3 + h * 64 + kf * 32 + quad * 8);

  f32x4 o[4][4], ol[4];
#pragma unroll
  for (int qi = 0; qi < 4; ++qi) {
    ol[qi] = f32x4{0.f, 0.f, 0.f, 0.f};
#pragma unroll
    for (int di = 0; di < 4; ++di) o[qi][di] = f32x4{0.f, 0.f, 0.f, 0.f};
  }
  bf16x8 ones;
#pragma unroll
  for (int i = 0; i < 8; ++i) ones[i] = (short)0x3F80;  // bf16 1.0

  const unsigned short* kp = qkv + (size_t)(b * Tt + l15) * E3 + Ee + h * 64 + quad * 8;
  const unsigned short* vp = vt + ((size_t)bh * 64 + l15) * Tt + quad * 8;

  bf16x8 kb[4][2], vb[4][2];
  // preload iter 0 K and V fragments
#pragma unroll
  for (int ki = 0; ki < 4; ++ki)
#pragma unroll
    for (int kf = 0; kf < 2; ++kf)
      kb[ki][kf] = *(const bf16x8*)(kp + (size_t)ki * 16 * E3 + kf * 32);
#pragma unroll
  for (int di = 0; di < 4; ++di)
#pragma unroll
    for (int kf = 0; kf < 2; ++kf)
      vb[di][kf] = *(const bf16x8*)(vp + di * 16 * Tt + kf * 32);

  auto body = [&](bool reload) __attribute__((always_inline)) {
    // ---- S^T tiles + exp + pack + LDS write; kb[ki] reloaded after last use
#pragma unroll
    for (int ki = 0; ki < 4; ++ki) {
      f32x4 s[4];
#pragma unroll
      for (int qi = 0; qi < 4; ++qi) {
        s[qi] = mfma16(kb[ki][0], qa[qi][0], f32x4{0.f, 0.f, 0.f, 0.f});
        s[qi] = mfma16(kb[ki][1], qa[qi][1], s[qi]);
      }
      if (reload) {
        kb[ki][0] = *(const bf16x8*)(kp + (size_t)ki * 16 * E3);
        kb[ki][1] = *(const bf16x8*)(kp + (size_t)ki * 16 * E3 + 32);
      }
#pragma unroll
      for (int qi = 0; qi < 4; ++qi) {
        const float e0 = __builtin_amdgcn_exp2f(s[qi][0]);
        const float e1 = __builtin_amdgcn_exp2f(s[qi][1]);
        const float e2 = __builtin_amdgcn_exp2f(s[qi][2]);
        const float e3 = __builtin_amdgcn_exp2f(s[qi][3]);
        uint2 w;  // truncate-to-bf16 pairs (bias cancels: denom uses same P)
        w.x = __builtin_amdgcn_perm(__float_as_uint(e1), __float_as_uint(e0), 0x07060302u);
        w.y = __builtin_amdgcn_perm(__float_as_uint(e3), __float_as_uint(e2), 0x07060302u);
        *(uint2*)(ps + (qi * 16 + l15) * 64 + (((ki * 4 + quad) ^ swz) << 2)) = w;
      }
    }

    // ---- P read-back (per-qi, 8 regs live) + ones/PV MFMAs
#pragma unroll
    for (int qi = 0; qi < 4; ++qi) {
      bf16x8 pa0 = *(const bf16x8*)(ps + (qi * 16 + l15) * 64 + (((quad * 2) ^ swz) << 2));
      bf16x8 pa1 = *(const bf16x8*)(ps + (qi * 16 + l15) * 64 + (((8 + quad * 2) ^ swz) << 2));
      ol[qi] = mfma16(pa0, ones, ol[qi]);
      ol[qi] = mfma16(pa1, ones, ol[qi]);
#pragma unroll
      for (int di = 0; di < 4; ++di) {
        o[qi][di] = mfma16(pa0, vb[di][0], o[qi][di]);
        o[qi][di] = mfma16(pa1, vb[di][1], o[qi][di]);
      }
    }
    // ---- vb reload for next iter (after last PV use; WAR-safe)
    if (reload) {
#pragma unroll
      for (int di = 0; di < 4; ++di)
#pragma unroll
        for (int kf = 0; kf < 2; ++kf)
          vb[di][kf] = *(const bf16x8*)(vp + di * 16 * Tt + kf * 32);
    }
  };

  for (int it = 0; it < Tt / 64 - 1; ++it) {
    kp += 64 * E3;   // advance FIRST: reloads inside body target the next tile
    vp += 64;
    body(true);
  }
  body(false);       // peeled last iteration: no prefetch, no OOB

  // epilogue: divide by l (same layout), store bf16 ctx
#pragma unroll
  for (int qi = 0; qi < 4; ++qi) {
    f32x4 inv;
#pragma unroll
    for (int r = 0; r < 4; ++r) inv[r] = 1.0f / ol[qi][r];
#pragma unroll
    for (int di = 0; di < 4; ++di)
#pragma unroll
      for (int r = 0; r < 4; ++r)
        ctx[(size_t)(b * Tt + q0 + qi * 16 + quad * 4 + r) * Ee + h * 64 + di * 16 + l15] =
            f2bf(o[qi][di][r] * inv[r]);
  }
}

// ---------------------------------------------------------------------------
extern "C" void kernel_launch(void* const* d_in, const int* in_sizes, int n_in,
                              void* d_out, int out_size, void* d_ws, size_t ws_size,
                              hipStream_t stream) {
  const float* query = (const float*)d_in[0];
  const float* in_w  = (const float*)d_in[1];
  const float* in_b  = (const float*)d_in[2];
  const float* out_w = (const float*)d_in[3];
  const float* out_b = (const float*)d_in[4];
  float* out = (float*)d_out;

  char* w = (char*)d_ws;
  unsigned short* qkvb = (unsigned short*)(w);                 // 48 MiB
  unsigned short* ctxb = (unsigned short*)(w + 50331648);      // 16 MiB
  unsigned short* qb   = (unsigned short*)(w + 67108864);      // 16 MiB
  unsigned short* wib  = (unsigned short*)(w + 83886080);      // 6 MiB
  unsigned short* wob  = (unsigned short*)(w + 90177536);      // 2 MiB
  unsigned short* vtb  = (unsigned short*)(w + 92274688);      // 16 MiB

  // 0) all fp32->bf16 conversions in one launch
  cvt_all<<<6144, 256, 0, stream>>>(query, in_w, out_w, qb, wib, wob);
  // 1) qkv = query @ in_w^T + in_b  (q part pre-scaled by log2e/8, bf16)
  gemm_bt<true, true><<<dim3(E3 / 128, Mm / 128), 256, 0, stream>>>(qb, wib, in_b, qkvb, E3, Ee);
  // 1b) pre-transpose V: vt[b][h][d][t]
  transpose_v<<<dim3(Bb * Hh, Tt / 128), 256, 0, stream>>>(qkvb, vtb);
  // 2) fused attention -> ctx (bf16, [B,T,E])
  attn_mfma4<<<dim3(Bb * Hh, Tt / 256), 256, 0, stream>>>(qkvb, vtb, ctxb);
  // 3) out = ctx @ out_w^T + out_b  (fp32 out)
  gemm_bt<false, false><<<dim3(Ee / 128, Mm / 128), 256, 0, stream>>>(ctxb, wob, out_b, out, Ee, Ee);
}